// Round 10
// baseline (234.015 us; speedup 1.0000x reference)
//
#include <hip/hip_runtime.h>
#include <hip/hip_bf16.h>
#include <math.h>

#define N_NODES 100000
#define DIM 128
#define HID 512
#define EDGES 600000
#define SCAN_CHUNK 1024
#define SCAN_NBLK ((N_NODES + SCAN_CHUNK - 1) / SCAN_CHUNK)  // 98
#define MROWS_PAD 100096
#define NCH1 (MROWS_PAD / 64)   // 1564 chunks for GEMM1
#define NCH2 (MROWS_PAD / 32)   // 3128 chunks for GEMM2
#define GEMM_GRID 512           // 2 blocks/CU

typedef short bf16x8 __attribute__((ext_vector_type(8)));
typedef float f32x4 __attribute__((ext_vector_type(4)));

// Swizzle convention (rule #21 both-sides): for every bf16 staging buffer
// (X, W1T, W2T, hdn) physical byte within a row = logical byte XOR
// ((row&7)<<4). XOR touches bits 4..6 only -> permutes 16-B slots within
// each 128-B chunk; linear copies (global_load_lds) preserve it; swizzled
// reads (global or ds) land right and are LDS-bank-conflict-free.

__device__ inline unsigned short f32_to_bf16(float f) {
    unsigned int u = __float_as_uint(f);
    u += 0x7fff + ((u >> 16) & 1);
    return (unsigned short)(u >> 16);
}

// fast GELU: tanh form via hw exp2 + rcp. |gelu_tanh - gelu_erf| <= ~5e-4.
__device__ inline float gelu_f(float x) {
    float x3 = x * x * x;
    float y = 0.7978845608028654f * x + 0.0356774081f * x3;
    float e = exp2f(y * 2.8853900817779268f);                 // exp(2y)
    float t = 1.0f - 2.0f * __builtin_amdgcn_rcpf(e + 1.0f);  // tanh(y)
    return 0.5f * x * (1.0f + t);
}

__device__ inline void gload16(const void* g, void* l) {
    __builtin_amdgcn_global_load_lds(
        (const __attribute__((address_space(1))) unsigned int*)g,
        (__attribute__((address_space(3))) unsigned int*)l,
        16, 0, 0);
}

// ---------------------------------------------------------------------------
// Fused prep kernel: W1 transpose | W2 transpose | h->bf16 convert | dst count
// ---------------------------------------------------------------------------
#define PREP_W1_BLKS 512
#define PREP_W2_BLKS 128
#define PREP_CONV_BLKS 12500                  // N_NODES*32/256
#define PREP_COUNT_BLKS ((EDGES + 255) / 256) // 2344
#define PREP_TOTAL (PREP_W1_BLKS + PREP_W2_BLKS + PREP_CONV_BLKS + PREP_COUNT_BLKS)

__global__ __launch_bounds__(256) void mgl_prep_kernel(
    const float* __restrict__ h, const int* __restrict__ ei,
    const float* __restrict__ W1, const float* __restrict__ W2,
    unsigned short* __restrict__ X, unsigned short* __restrict__ W1T,
    unsigned short* __restrict__ W2T, int* __restrict__ cnt)
{
    int b = blockIdx.x;
    if (b < PREP_W1_BLKS) {
        int n = b;                       // 0..511
        int k = threadIdx.x;             // 0..255
        unsigned short val = f32_to_bf16(W1[(size_t)k * HID + n]);
        int byteoff = (k * 2) ^ ((n & 7) << 4);
        *(unsigned short*)((char*)(W1T + (size_t)n * 256) + byteoff) = val;
        return;
    }
    b -= PREP_W1_BLKS;
    if (b < PREP_W2_BLKS) {
        int n = b;                       // 0..127
        #pragma unroll
        for (int it = 0; it < 2; ++it) {
            int k = threadIdx.x + it * 256;  // 0..511
            unsigned short val = f32_to_bf16(W2[(size_t)k * DIM + n]);
            int byteoff = (k * 2) ^ ((n & 7) << 4);
            *(unsigned short*)((char*)(W2T + (size_t)n * 512) + byteoff) = val;
        }
        return;
    }
    b -= PREP_W2_BLKS;
    if (b < PREP_CONV_BLKS) {
        int t = b * 256 + threadIdx.x;
        if (t >= N_NODES * (DIM / 4)) return;
        int node = t >> 5;               // 32 float4 per node
        int c4 = t & 31;
        float4 v = *(const float4*)(h + (size_t)node * DIM + c4 * 4);
        ushort4 p;
        p.x = f32_to_bf16(v.x); p.y = f32_to_bf16(v.y);
        p.z = f32_to_bf16(v.z); p.w = f32_to_bf16(v.w);
        int byteoff = (c4 * 8) ^ ((node & 7) << 4);
        *(ushort4*)((char*)(X + (size_t)node * 256) + byteoff) = p;
        return;
    }
    b -= PREP_CONV_BLKS;
    {
        int e = b * 256 + threadIdx.x;
        if (e < EDGES) atomicAdd(&cnt[ei[EDGES + e]], 1);
    }
}

// ---------------------------------------------------------------------------
// Scan (3 kernels)
// ---------------------------------------------------------------------------
__global__ __launch_bounds__(256) void mgl_scan_block_kernel(
    const int* __restrict__ cnt, int* __restrict__ row_start, int* __restrict__ bsum)
{
    __shared__ int sdata[256];
    int t = threadIdx.x;
    int base = blockIdx.x * SCAN_CHUNK + t * 4;
    int v[4];
    #pragma unroll
    for (int i = 0; i < 4; ++i) {
        int idx = base + i;
        v[i] = (idx < N_NODES) ? cnt[idx] : 0;
    }
    int tsum = v[0] + v[1] + v[2] + v[3];
    sdata[t] = tsum;
    __syncthreads();
    for (int off = 1; off < 256; off <<= 1) {
        int x = (t >= off) ? sdata[t - off] : 0;
        __syncthreads();
        sdata[t] += x;
        __syncthreads();
    }
    int run = (t > 0) ? sdata[t - 1] : 0;
    #pragma unroll
    for (int i = 0; i < 4; ++i) {
        int idx = base + i;
        if (idx < N_NODES) row_start[idx] = run;
        run += v[i];
    }
    if (t == 255) bsum[blockIdx.x] = sdata[255];
}

__global__ __launch_bounds__(128) void mgl_scan_bsum_kernel(int* __restrict__ bsum)
{
    __shared__ int sd[128];
    int t = threadIdx.x;
    int v = (t < SCAN_NBLK) ? bsum[t] : 0;
    sd[t] = v;
    __syncthreads();
    for (int off = 1; off < 128; off <<= 1) {
        int x = (t >= off) ? sd[t - off] : 0;
        __syncthreads();
        sd[t] += x;
        __syncthreads();
    }
    if (t < SCAN_NBLK) bsum[t] = sd[t] - v;  // exclusive
}

__global__ __launch_bounds__(256) void mgl_scan_add_kernel(
    int* __restrict__ row_start, const int* __restrict__ bsum)
{
    int i = blockIdx.x * 256 + threadIdx.x;
    if (i < N_NODES) row_start[i] += bsum[i / SCAN_CHUNK];
    if (i == 0) row_start[N_NODES] = EDGES;
}

// ---------------------------------------------------------------------------
// Fill: consume leftover counts with atomicSub (cnt ends 0 -> deterministic).
// ---------------------------------------------------------------------------
__global__ __launch_bounds__(256) void mgl_fill_kernel(
    const int* __restrict__ ei, const int* __restrict__ row_start,
    int* __restrict__ cnt, int* __restrict__ csr)
{
    int e = blockIdx.x * 256 + threadIdx.x;
    if (e >= EDGES) return;
    int s = ei[e];
    int t = ei[EDGES + e];
    int pos = atomicSub(&cnt[t], 1) - 1;
    csr[row_start[t] + pos] = s;
}

// ---------------------------------------------------------------------------
// Gather-mean (one wave/node): neighbor ids loaded 64-wide, shfl-broadcast.
// ---------------------------------------------------------------------------
__global__ __launch_bounds__(256) void mgl_gather_mean_kernel(
    const unsigned short* __restrict__ Xb, const int* __restrict__ row_start,
    const int* __restrict__ csr, unsigned short* __restrict__ X)
{
    int v = blockIdx.x * 4 + (threadIdx.x >> 6);
    if (v >= N_NODES) return;
    int lane = threadIdx.x & 63;
    int beg = row_start[v];
    int nb = row_start[v + 1] - beg;
    int laneByte = lane * 4;
    const char* xb = (const char*)Xb;

    if (nb > 0) {
        float2 acc = make_float2(0.f, 0.f);
        for (int base = 0; base < nb; base += 64) {
            int rem = nb - base; if (rem > 64) rem = 64;
            int sv = (lane < rem) ? csr[beg + base + lane] : 0;
            for (int j = 0; j < rem; ++j) {
                int s = __shfl(sv, j);
                unsigned int pk = *(const unsigned int*)(
                    xb + (size_t)s * 512 + (laneByte ^ ((s & 7) << 4)));
                acc.x += __uint_as_float(pk << 16);
                acc.y += __uint_as_float(pk & 0xffff0000u);
            }
        }
        float inv = 1.f / (float)nb;
        unsigned int po = (unsigned int)f32_to_bf16(acc.x * inv) |
                          ((unsigned int)f32_to_bf16(acc.y * inv) << 16);
        *(unsigned int*)((char*)(X + (size_t)v * 256) +
                         ((256 + laneByte) ^ ((v & 7) << 4))) = po;
    } else {
        unsigned int pk = *(const unsigned int*)(
            xb + (size_t)v * 512 + (laneByte ^ ((v & 7) << 4)));
        *(unsigned int*)((char*)(X + (size_t)v * 256) +
                         ((256 + laneByte) ^ ((v & 7) << 4))) = pk;
    }
}

// ---------------------------------------------------------------------------
// GEMM1 (hdn = gelu(X @ W1 + b1)): W1 RESIDENT IN REGISTERS per wave.
// 8 waves x 64 n-cols = N=512. X streamed in 64-row full-K chunks (32 KB)
// via a 2-SLOT ring (64 KB LDS -> 2 blocks/CU), depth-1 prefetch, one
// barrier per chunk, 128 MFMA/wave between barriers.
// vmcnt discipline (stores counted, in-order): iter0 vmcnt(0) drains
// W1+bias+L0; steady vmcnt(16) = allow the 16 hdn stores of chunk j-1 (and
// nothing newer than L(j)) -> L(j) guaranteed retired, stores NOT drained.
// ---------------------------------------------------------------------------
__global__ __launch_bounds__(512, 2) void mgl_mlp1_kernel(
    const unsigned short* __restrict__ W1T,  // [512][256] bf16 swizzled
    const unsigned short* __restrict__ Xr,   // [MROWS_PAD][256] bf16 swizzled
    const float* __restrict__ b1f,
    unsigned short* __restrict__ hdn)        // [MROWS_PAD][512] bf16 swizzled
{
    __shared__ char ldsX[2 * 32768];
    const int tid = threadIdx.x;
    const int w = tid >> 6, l = tid & 63;
    const int r16 = l & 15, kq = l >> 4;
    const int rmask = (r16 & 7) << 4;
    const int n0w = w * 64;

    // resident W1 fragments + bias (drained by iter-0 vmcnt(0))
    bf16x8 a1[4][8];
    #pragma unroll
    for (int nb = 0; nb < 4; ++nb) {
        const char* wrow = (const char*)W1T + (size_t)(n0w + nb * 16 + r16) * 512;
        #pragma unroll
        for (int ks = 0; ks < 8; ++ks)
            a1[nb][ks] = *(const bf16x8*)(wrow + ((ks * 64 + kq * 16) ^ rmask));
    }
    float4 b1v[4];
    #pragma unroll
    for (int nb = 0; nb < 4; ++nb)
        b1v[nb] = *(const float4*)(b1f + n0w + nb * 16 + kq * 4);

    const int bid = blockIdx.x;
    const int nch = (NCH1 - bid + GEMM_GRID - 1) / GEMM_GRID;

    auto stage = [&](int slot, int cj) {       // 64 rows x 512 B contiguous
        const char* src = (const char*)Xr + (size_t)cj * 32768;
        char* dst = ldsX + slot * 32768;
        #pragma unroll
        for (int i = 0; i < 4; ++i) {
            int off = i * 8192 + tid * 16;
            gload16(src + off, dst + off);
        }
    };

    stage(0, bid);

    for (int j = 0; j < nch; ++j) {
        if (j == 0) asm volatile("s_waitcnt vmcnt(0)" ::: "memory");
        else        asm volatile("s_waitcnt vmcnt(16)" ::: "memory");
        __builtin_amdgcn_s_barrier();          // all waves see chunk j staged
        asm volatile("" ::: "memory");
        if (j + 1 < nch) stage((j + 1) & 1, bid + (j + 1) * GEMM_GRID);

        const char* bX = ldsX + (j & 1) * 32768;
        f32x4 acc[4][4] = {};
        #pragma unroll
        for (int ks = 0; ks < 8; ++ks) {
            bf16x8 b[4];
            #pragma unroll
            for (int mb = 0; mb < 4; ++mb)
                b[mb] = *(const bf16x8*)(bX + (mb * 16 + r16) * 512 +
                                         ((ks * 64 + kq * 16) ^ rmask));
            #pragma unroll
            for (int mb = 0; mb < 4; ++mb)
                #pragma unroll
                for (int nb = 0; nb < 4; ++nb)
                    acc[mb][nb] = __builtin_amdgcn_mfma_f32_16x16x32_bf16(
                        a1[nb][ks], b[mb], acc[mb][nb], 0, 0, 0);
        }

        // epilogue: bias + gelu -> hdn (bf16, swizzled); 16 stores, drain
        // deferred to next iter's vmcnt(16).
        const size_t m0c = (size_t)(bid + j * GEMM_GRID) * 64;
        #pragma unroll
        for (int mb = 0; mb < 4; ++mb) {
            size_t m = m0c + mb * 16 + r16;
            char* hrow = (char*)hdn + m * 1024;
            #pragma unroll
            for (int nb = 0; nb < 4; ++nb) {
                int nc = n0w + nb * 16 + kq * 4;
                ushort4 pk;
                pk.x = f32_to_bf16(gelu_f(acc[mb][nb][0] + b1v[nb].x));
                pk.y = f32_to_bf16(gelu_f(acc[mb][nb][1] + b1v[nb].y));
                pk.z = f32_to_bf16(gelu_f(acc[mb][nb][2] + b1v[nb].z));
                pk.w = f32_to_bf16(gelu_f(acc[mb][nb][3] + b1v[nb].w));
                *(ushort4*)(hrow + ((nc * 2) ^ rmask)) = pk;
            }
        }
    }
}

// ---------------------------------------------------------------------------
// GEMM2 (out = hdn @ W2 + b2): W2 RESIDENT IN REGISTERS per wave.
// 8 waves x 16 n-cols = N=128. hdn streamed in 32-row full-K chunks (32 KB)
// via 2-slot ring; iter0 vmcnt(0), steady vmcnt(2) (allow 2 out stores).
// ---------------------------------------------------------------------------
__global__ __launch_bounds__(512, 2) void mgl_mlp2_kernel(
    const unsigned short* __restrict__ W2T,  // [128][512] bf16 swizzled
    const unsigned short* __restrict__ hdn,  // [MROWS_PAD][512] bf16 swizzled
    const float* __restrict__ b2f,
    float* __restrict__ outp)
{
    __shared__ char ldsH[2 * 32768];
    const int tid = threadIdx.x;
    const int w = tid >> 6, l = tid & 63;
    const int r16 = l & 15, kq = l >> 4;
    const int rmask = (r16 & 7) << 4;

    bf16x8 a2[16];
    {
        const char* wrow = (const char*)W2T + (size_t)(w * 16 + r16) * 1024;
        #pragma unroll
        for (int ks = 0; ks < 16; ++ks)
            a2[ks] = *(const bf16x8*)(wrow + ((ks * 64 + kq * 16) ^ rmask));
    }
    float4 b2v = *(const float4*)(b2f + w * 16 + kq * 4);

    const int bid = blockIdx.x;
    const int nch = (NCH2 - bid + GEMM_GRID - 1) / GEMM_GRID;

    auto stage = [&](int slot, int cj) {       // 32 rows x 1024 B contiguous
        const char* src = (const char*)hdn + (size_t)cj * 32768;
        char* dst = ldsH + slot * 32768;
        #pragma unroll
        for (int i = 0; i < 4; ++i) {
            int off = i * 8192 + tid * 16;
            gload16(src + off, dst + off);
        }
    };

    stage(0, bid);

    for (int j = 0; j < nch; ++j) {
        if (j == 0) asm volatile("s_waitcnt vmcnt(0)" ::: "memory");
        else        asm volatile("s_waitcnt vmcnt(2)" ::: "memory");
        __builtin_amdgcn_s_barrier();
        asm volatile("" ::: "memory");
        if (j + 1 < nch) stage((j + 1) & 1, bid + (j + 1) * GEMM_GRID);

        const char* bH = ldsH + (j & 1) * 32768;
        f32x4 acc[2] = {};
        #pragma unroll
        for (int ks = 0; ks < 16; ++ks) {
            bf16x8 b[2];
            #pragma unroll
            for (int mb = 0; mb < 2; ++mb)
                b[mb] = *(const bf16x8*)(bH + (mb * 16 + r16) * 1024 +
                                         ((ks * 64 + kq * 16) ^ rmask));
            #pragma unroll
            for (int mb = 0; mb < 2; ++mb)
                acc[mb] = __builtin_amdgcn_mfma_f32_16x16x32_bf16(
                    a2[ks], b[mb], acc[mb], 0, 0, 0);
        }

        const size_t m0c = (size_t)(bid + j * GEMM_GRID) * 32;
        #pragma unroll
        for (int mb = 0; mb < 2; ++mb) {
            size_t m = m0c + mb * 16 + r16;
            if (m < N_NODES) {
                float4 o;
                o.x = acc[mb][0] + b2v.x;
                o.y = acc[mb][1] + b2v.y;
                o.z = acc[mb][2] + b2v.z;
                o.w = acc[mb][3] + b2v.w;
                *(float4*)(outp + m * DIM + w * 16 + kq * 4) = o;
            }
        }
    }
}

// ---------------------------------------------------------------------------
extern "C" void kernel_launch(void* const* d_in, const int* in_sizes, int n_in,
                              void* d_out, int out_size, void* d_ws, size_t ws_size,
                              hipStream_t stream) {
    const float* h  = (const float*)d_in[0];
    const int*   ei = (const int*)d_in[1];
    const float* W1 = (const float*)d_in[2];
    const float* b1 = (const float*)d_in[3];
    const float* W2 = (const float*)d_in[4];
    const float* b2 = (const float*)d_in[5];
    float* out = (float*)d_out;

    // workspace layout
    unsigned short* X   = (unsigned short*)d_ws;             // MROWS_PAD*256 bf16
    unsigned short* hdn = X + (size_t)MROWS_PAD * 256;       // MROWS_PAD*512 bf16
    unsigned short* W1T = hdn + (size_t)MROWS_PAD * 512;     // 512*256 bf16
    unsigned short* W2T = W1T + 512 * 256;                   // 128*512 bf16
    int* cnt = (int*)(W2T + 128 * 512);                      // N
    int* row_start = cnt + N_NODES;                          // N+1
    int* bsum = row_start + N_NODES + 1;                     // 128
    int* csr = bsum + 128;                                   // E

    hipMemsetAsync(cnt, 0, N_NODES * sizeof(int), stream);
    mgl_prep_kernel<<<PREP_TOTAL, 256, 0, stream>>>(h, ei, W1, W2, X, W1T, W2T, cnt);
    mgl_scan_block_kernel<<<SCAN_NBLK, 256, 0, stream>>>(cnt, row_start, bsum);
    mgl_scan_bsum_kernel<<<1, 128, 0, stream>>>(bsum);
    mgl_scan_add_kernel<<<(N_NODES + 255) / 256, 256, 0, stream>>>(row_start, bsum);
    mgl_fill_kernel<<<(EDGES + 255) / 256, 256, 0, stream>>>(ei, row_start, cnt, csr);
    mgl_gather_mean_kernel<<<(N_NODES + 3) / 4, 256, 0, stream>>>(X, row_start, csr, X);

    // MLP: W-in-register streaming GEMMs, 512 blocks each (2/CU)
    mgl_mlp1_kernel<<<GEMM_GRID, 512, 0, stream>>>(W1T, X, b1, hdn);
    mgl_mlp2_kernel<<<GEMM_GRID, 512, 0, stream>>>(W2T, hdn, b2, out);
}